// Round 15
// baseline (278.244 us; speedup 1.0000x reference)
//
#include <hip/hip_runtime.h>
#include <cstdint>

#define B_DIM 16
#define C_DIM 512
#define N_DIM 4096

typedef __bf16 bf16x8 __attribute__((ext_vector_type(8)));
typedef unsigned short u16x8 __attribute__((ext_vector_type(8)));
typedef unsigned short u16x4 __attribute__((ext_vector_type(4)));
typedef unsigned int u32x4 __attribute__((ext_vector_type(4)));
typedef unsigned int u32x2 __attribute__((ext_vector_type(2)));
typedef float f32x4 __attribute__((ext_vector_type(4)));

__device__ __forceinline__ bf16x8 as_bf(u16x8 v) { return __builtin_bit_cast(bf16x8, v); }

// [hi16(ub) : hi16(ua)] in one v_perm_b32 (ua -> low half)
__device__ __forceinline__ unsigned pack_hi(unsigned ua, unsigned ub) {
    return __builtin_amdgcn_perm(ub, ua, 0x07060302u);
}
__device__ __forceinline__ unsigned rne_pack(float a, float b) {
    unsigned ua = __float_as_uint(a);
    ua += 0x7fffu + ((ua >> 16) & 1u);
    unsigned ub = __float_as_uint(b);
    ub += 0x7fffu + ((ub >> 16) & 1u);
    return pack_hi(ua, ub);
}

#define BT 128
#define GBK 64   // gram K-step (r15: halves barriers vs 32, r10-analog)
#define GBKP 72  // gram LDS row pad (ushorts): 144B rows, 2-way banks max
#define GK 64    // gemm2 K-step
#define GKP 72   // gemm2 LDS row pad

// ---------------------------------------------------------------------------
// Kernel 1: partial Gram  E_s[c,d] = sum_{n in slice s} Q[n,c] Q[n,d]
// Split bf16 (truncating): E ~ hi*hi + hi*lo + lo*hi.  Upper-triangle tiles
// only, mirrored on store.  SK=8 when ws allows.  r15: K-step 64 (8 barriers
// per block instead of 16 -- r14 PMC: MfmaUtil 25 + VALU 22, barrier-bound).
// NOTE (r11/r12): do NOT pre-materialize a bf16 x copy for gemm2.
// Plain launch_bounds: (256,4) caps VGPR at 64 -> spill catastrophe (r3).
// ---------------------------------------------------------------------------
__global__ __launch_bounds__(256) void gram_kernel(const float* __restrict__ x,
                                                   float* __restrict__ part, int kshift) {
    const int nwg = 10 * gridDim.z;
    const int chunk = nwg >> 3;
    const int flat = blockIdx.x + 10 * blockIdx.z;
    const int swz = (flat & 7) * chunk + (flat >> 3);
    const int tile = swz % 10;
    const int z = swz / 10;
    const int s = z & ((1 << kshift) - 1);
    const int b = z >> kshift;
    static const int TI[10] = {0, 0, 0, 0, 1, 1, 1, 2, 2, 3};
    static const int TJ[10] = {0, 1, 2, 3, 1, 2, 3, 2, 3, 3};
    const int c0 = TI[tile] * BT;
    const int d0 = TJ[tile] * BT;
    const bool diag = (c0 == d0);

    const float* __restrict__ Q = x + (size_t)b * (N_DIM * C_DIM);
    float* __restrict__ E = part + ((size_t)s * B_DIM + b) * (C_DIM * C_DIM);

    __shared__ unsigned short lAh[BT][GBKP];
    __shared__ unsigned short lAl[BT][GBKP];
    __shared__ unsigned short lBh[BT][GBKP];
    __shared__ unsigned short lBl[BT][GBKP];  // 73.7 KB total

    const int tid = threadIdx.x;
    const int lane = tid & 63;
    const int w = tid >> 6;
    const int moff = (w & 1) * 64;
    const int noff = (w >> 1) * 64;
    const int frow = lane & 15;
    const int fk = (lane >> 4) * 8;

    f32x4 acc[4][4];
#pragma unroll
    for (int m = 0; m < 4; ++m)
#pragma unroll
        for (int n = 0; n < 4; ++n) acc[m][n] = (f32x4){0.f, 0.f, 0.f, 0.f};

    const int cc = tid & 127;
    const int kh = tid >> 7;  // 0/1: rows kh*32 .. kh*32+32 of the K-step

    const int klen = N_DIM >> kshift;
    const float* gA = Q + (size_t)(s * klen + kh * 32) * C_DIM + (c0 + cc);
    const float* gB = Q + (size_t)(s * klen + kh * 32) * C_DIM + (d0 + cc);

    const unsigned short(*pBh)[GBKP] = diag ? lAh : lBh;
    const unsigned short(*pBl)[GBKP] = diag ? lAl : lBl;

    float av[32], bv[32];
#pragma unroll
    for (int i = 0; i < 32; ++i) av[i] = gA[(size_t)i * C_DIM];
    if (!diag) {
#pragma unroll
        for (int i = 0; i < 32; ++i) bv[i] = gB[(size_t)i * C_DIM];
    }
    gA += (size_t)GBK * C_DIM;
    gB += (size_t)GBK * C_DIM;

    const int T = klen / GBK;
    for (int t = 0; t < T; ++t) {
        // convert current prefetched tile (v_perm packing, trunc hi + residual lo)
        u32x4 ah[4], al[4], bh[4], bl[4];
#pragma unroll
        for (int g = 0; g < 4; ++g)
#pragma unroll
            for (int p = 0; p < 4; ++p) {
                const int j = g * 8 + p * 2;
                unsigned u0 = __float_as_uint(av[j]), u1 = __float_as_uint(av[j + 1]);
                ah[g][p] = pack_hi(u0, u1);
                float r0 = av[j] - __uint_as_float(u0 & 0xffff0000u);
                float r1 = av[j + 1] - __uint_as_float(u1 & 0xffff0000u);
                al[g][p] = pack_hi(__float_as_uint(r0), __float_as_uint(r1));
            }
        if (!diag) {
#pragma unroll
            for (int g = 0; g < 4; ++g)
#pragma unroll
                for (int p = 0; p < 4; ++p) {
                    const int j = g * 8 + p * 2;
                    unsigned u0 = __float_as_uint(bv[j]), u1 = __float_as_uint(bv[j + 1]);
                    bh[g][p] = pack_hi(u0, u1);
                    float r0 = bv[j] - __uint_as_float(u0 & 0xffff0000u);
                    float r1 = bv[j + 1] - __uint_as_float(u1 & 0xffff0000u);
                    bl[g][p] = pack_hi(__float_as_uint(r0), __float_as_uint(r1));
                }
        }

        __syncthreads();  // previous iteration's LDS reads done
#pragma unroll
        for (int g = 0; g < 4; ++g) {
            *(u16x8*)&lAh[cc][kh * 32 + g * 8] = __builtin_bit_cast(u16x8, ah[g]);
            *(u16x8*)&lAl[cc][kh * 32 + g * 8] = __builtin_bit_cast(u16x8, al[g]);
        }
        if (!diag) {
#pragma unroll
            for (int g = 0; g < 4; ++g) {
                *(u16x8*)&lBh[cc][kh * 32 + g * 8] = __builtin_bit_cast(u16x8, bh[g]);
                *(u16x8*)&lBl[cc][kh * 32 + g * 8] = __builtin_bit_cast(u16x8, bl[g]);
            }
        }
        __syncthreads();

        // issue next tile's loads; latency hides under MFMA below
        if (t + 1 < T) {
#pragma unroll
            for (int i = 0; i < 32; ++i) av[i] = gA[(size_t)i * C_DIM];
            if (!diag) {
#pragma unroll
                for (int i = 0; i < 32; ++i) bv[i] = gB[(size_t)i * C_DIM];
            }
            gA += (size_t)GBK * C_DIM;
            gB += (size_t)GBK * C_DIM;
        }

#pragma unroll
        for (int sub = 0; sub < 2; ++sub) {
            const int sk = sub * 32 + fk;
            bf16x8 fbh[4], fbl[4];
#pragma unroll
            for (int n = 0; n < 4; ++n) {
                fbh[n] = as_bf(*(const u16x8*)&pBh[noff + n * 16 + frow][sk]);
                fbl[n] = as_bf(*(const u16x8*)&pBl[noff + n * 16 + frow][sk]);
            }
#pragma unroll
            for (int m = 0; m < 4; ++m) {
                bf16x8 fah = as_bf(*(const u16x8*)&lAh[moff + m * 16 + frow][sk]);
                bf16x8 fal = as_bf(*(const u16x8*)&lAl[moff + m * 16 + frow][sk]);
#pragma unroll
                for (int n = 0; n < 4; ++n) {
                    acc[m][n] = __builtin_amdgcn_mfma_f32_16x16x32_bf16(fah, fbh[n], acc[m][n], 0, 0, 0);
                    acc[m][n] = __builtin_amdgcn_mfma_f32_16x16x32_bf16(fah, fbl[n], acc[m][n], 0, 0, 0);
                    acc[m][n] = __builtin_amdgcn_mfma_f32_16x16x32_bf16(fal, fbh[n], acc[m][n], 0, 0, 0);
                }
            }
        }
    }

#pragma unroll
    for (int m = 0; m < 4; ++m)
#pragma unroll
        for (int n = 0; n < 4; ++n) {
            const int r = c0 + moff + m * 16 + (lane >> 4) * 4;
            const int col = d0 + noff + n * 16 + frow;
#pragma unroll
            for (int i = 0; i < 4; ++i)
                E[(size_t)(r + i) * C_DIM + col] = acc[m][n][i];
        }
    if (!diag) {
#pragma unroll
        for (int m = 0; m < 4; ++m)
#pragma unroll
            for (int n = 0; n < 4; ++n) {
                const int r = c0 + moff + m * 16 + (lane >> 4) * 4;
                const int col = d0 + noff + n * 16 + frow;
#pragma unroll
                for (int i = 0; i < 4; ++i)
                    E[(size_t)col * C_DIM + (r + i)] = acc[m][n][i];
            }
    }
}

// ---------------------------------------------------------------------------
// Kernel 2a/2b: column max of batch-0 energy (sum of partials on the fly)
// ---------------------------------------------------------------------------
__global__ __launch_bounds__(256) void colmax1(const float* __restrict__ part,
                                               float* __restrict__ pmax, int sk) {
    const int d = blockIdx.x * 256 + threadIdx.x;
    const int cg = blockIdx.y;
    const size_t PS = (size_t)B_DIM * C_DIM * C_DIM;
    float m = -3.4e38f;
    for (int c = cg * 16; c < cg * 16 + 16; ++c) {
        float e = 0.f;
        for (int s = 0; s < sk; ++s) e += part[(size_t)s * PS + (size_t)c * C_DIM + d];
        m = fmaxf(m, e);
    }
    pmax[cg * C_DIM + d] = m;
}

__global__ __launch_bounds__(256) void colmax2(const float* __restrict__ pmax,
                                               float* __restrict__ mx) {
    const int d = blockIdx.x * 256 + threadIdx.x;
    float m = pmax[d];
#pragma unroll
    for (int g = 1; g < 32; ++g) m = fmaxf(m, pmax[g * C_DIM + d]);
    mx[d] = m;
}

// ---------------------------------------------------------------------------
// Kernel 3: row softmax of (mx[d] - sum_s E_s[b,c,d]).
// Emits bf16 (RNE) att, striped into the BACK HALF of each partial-0 row:
// u16 index wid*1024 + 512 + d.  Race-free: each wave fully reads its row
// before any lane writes it; no other row touches it.
// ---------------------------------------------------------------------------
__global__ __launch_bounds__(256) void softmax_kernel(float* __restrict__ part,
                                                      const float* __restrict__ mx, int sk) {
    const int wid = blockIdx.x * 4 + (threadIdx.x >> 6);  // row index in [0, B*C)
    const int lane = threadIdx.x & 63;
    const size_t PS = (size_t)B_DIM * C_DIM * C_DIM;

    f32x4 ea = (f32x4){0.f, 0.f, 0.f, 0.f}, eb = ea;
    for (int s = 0; s < sk; ++s) {
        const f32x4* row = (const f32x4*)(part + (size_t)s * PS + (size_t)wid * C_DIM + lane * 8);
        ea += row[0];
        eb += row[1];
    }
    f32x4 ma = *(const f32x4*)&mx[lane * 8];
    f32x4 mb = *(const f32x4*)&mx[lane * 8 + 4];

    float v[8];
#pragma unroll
    for (int j = 0; j < 4; ++j) v[j] = ma[j] - ea[j];
#pragma unroll
    for (int j = 0; j < 4; ++j) v[4 + j] = mb[j] - eb[j];

    float rm = v[0];
#pragma unroll
    for (int j = 1; j < 8; ++j) rm = fmaxf(rm, v[j]);
#pragma unroll
    for (int st = 1; st < 64; st <<= 1) rm = fmaxf(rm, __shfl_xor(rm, st));

    float p[8];
    float sum = 0.f;
#pragma unroll
    for (int j = 0; j < 8; ++j) {
        p[j] = expf(v[j] - rm);
        sum += p[j];
    }
#pragma unroll
    for (int st = 1; st < 64; st <<= 1) sum += __shfl_xor(sum, st);

    const float inv = 1.f / sum;
    u32x4 o;
#pragma unroll
    for (int q = 0; q < 4; ++q) o[q] = rne_pack(p[2 * q] * inv, p[2 * q + 1] * inv);
    unsigned short* arow = (unsigned short*)part + (size_t)wid * 1024 + 512;
    *(u16x8*)&arow[lane * 8] = __builtin_bit_cast(u16x8, o);
}

// ---------------------------------------------------------------------------
// Kernel 4: out[b,c,n] = gamma * sum_d att[b,c,d] * Q[n,d] + x[b,c,n]
// r10's measured-best K-loop (128x128, 256 thr, GK=64, dbuf, tracked-reg
// staging, XCD swizzle, plain bounds) + r14's LDS-transposed float4 epilogue.
// ---------------------------------------------------------------------------
__global__ __launch_bounds__(256) void gemm2_kernel(const unsigned short* __restrict__ att16,
                                                    const float* __restrict__ x,
                                                    const float* __restrict__ gamma,
                                                    float* __restrict__ out) {
    const int flat = blockIdx.x;
    const int swz = (flat & 7) * 256 + (flat >> 3);  // 2048 % 8 == 0: bijective
    const int c0 = (swz & 3) * BT;
    const int n0 = ((swz >> 2) & 31) * BT;
    const int b = swz >> 7;

    const float* __restrict__ Q = x + (size_t)b * (N_DIM * C_DIM);
    float* __restrict__ Ob = out + (size_t)b * (C_DIM * N_DIM);
    const unsigned short* __restrict__ Ab = att16 + (size_t)(b * C_DIM + c0) * 1024 + 512;

    // [buf][A=0/B=1][row][col]; also reused as 128x128 f32 tile in epilogue
    __shared__ unsigned short smem[2][2][BT][GKP];  // 73.7 KB

    const int tid = threadIdx.x;
    const int lane = tid & 63;
    const int w = tid >> 6;
    const int moff = (w & 1) * 64;
    const int noff = (w >> 1) * 64;
    const int frow = lane & 15;
    const int fq = lane >> 4;  // 0..3
    const int fk = fq * 8;

    f32x4 acc[4][4];
#pragma unroll
    for (int m = 0; m < 4; ++m)
#pragma unroll
        for (int n = 0; n < 4; ++n) acc[m][n] = (f32x4){0.f, 0.f, 0.f, 0.f};

    // A staging: f = tid + 256*i (i<4): row f>>3 (0..127), u16 chunk (f&7)*8
    const int ar = tid >> 3;          // +32*i
    const int ac = (tid & 7) * 8;     // u16 col
    const int br = ar;
    const int bc = (tid & 7) * 8;     // f32 col

    u16x8 pa[4];
    float4 rb[4][2];
#pragma unroll
    for (int i = 0; i < 4; ++i)
        pa[i] = *(const u16x8*)&Ab[(size_t)(ar + 32 * i) * 1024 + ac];
#pragma unroll
    for (int i = 0; i < 4; ++i) {
        rb[i][0] = *(const float4*)&Q[(size_t)(n0 + br + 32 * i) * C_DIM + bc];
        rb[i][1] = *(const float4*)&Q[(size_t)(n0 + br + 32 * i) * C_DIM + bc + 4];
    }
#pragma unroll
    for (int i = 0; i < 4; ++i)
        *(u16x8*)&smem[0][0][ar + 32 * i][ac] = pa[i];
#pragma unroll
    for (int i = 0; i < 4; ++i) {
        u32x4 pk = {pack_hi(__float_as_uint(rb[i][0].x), __float_as_uint(rb[i][0].y)),
                    pack_hi(__float_as_uint(rb[i][0].z), __float_as_uint(rb[i][0].w)),
                    pack_hi(__float_as_uint(rb[i][1].x), __float_as_uint(rb[i][1].y)),
                    pack_hi(__float_as_uint(rb[i][1].z), __float_as_uint(rb[i][1].w))};
        *(u16x8*)&smem[0][1][br + 32 * i][bc] = __builtin_bit_cast(u16x8, pk);
    }

    int cur = 0;
    for (int t = 0; t < 8; ++t) {
        __syncthreads();  // buf[cur] staged; prev iteration's reads done
        if (t < 7) {
            const int k1 = (t + 1) * GK;
#pragma unroll
            for (int i = 0; i < 4; ++i)
                pa[i] = *(const u16x8*)&Ab[(size_t)(ar + 32 * i) * 1024 + k1 + ac];
#pragma unroll
            for (int i = 0; i < 4; ++i) {
                rb[i][0] = *(const float4*)&Q[(size_t)(n0 + br + 32 * i) * C_DIM + k1 + bc];
                rb[i][1] = *(const float4*)&Q[(size_t)(n0 + br + 32 * i) * C_DIM + k1 + bc + 4];
            }
        }

#pragma unroll
        for (int sub = 0; sub < 2; ++sub) {
            const int sk = sub * 32 + fk;
            bf16x8 fb[4];
#pragma unroll
            for (int n = 0; n < 4; ++n)
                fb[n] = as_bf(*(const u16x8*)&smem[cur][1][noff + n * 16 + frow][sk]);
#pragma unroll
            for (int m = 0; m < 4; ++m) {
                const bf16x8 fa = as_bf(*(const u16x8*)&smem[cur][0][moff + m * 16 + frow][sk]);
#pragma unroll
                for (int n = 0; n < 4; ++n)
                    acc[m][n] = __builtin_amdgcn_mfma_f32_16x16x32_bf16(fa, fb[n], acc[m][n], 0, 0, 0);
            }
        }

        if (t < 7) {
            const int nb = cur ^ 1;
#pragma unroll
            for (int i = 0; i < 4; ++i)
                *(u16x8*)&smem[nb][0][ar + 32 * i][ac] = pa[i];
#pragma unroll
            for (int i = 0; i < 4; ++i) {
                u32x4 pk = {pack_hi(__float_as_uint(rb[i][0].x), __float_as_uint(rb[i][0].y)),
                            pack_hi(__float_as_uint(rb[i][0].z), __float_as_uint(rb[i][0].w)),
                            pack_hi(__float_as_uint(rb[i][1].x), __float_as_uint(rb[i][1].y)),
                            pack_hi(__float_as_uint(rb[i][1].z), __float_as_uint(rb[i][1].w))};
                *(u16x8*)&smem[nb][1][br + 32 * i][bc] = __builtin_bit_cast(u16x8, pk);
            }
        }
        cur ^= 1;
    }

    // -------- epilogue: transpose acc through LDS, then float4 x/out --------
    __syncthreads();  // all K-loop LDS reads complete; LDS is free
    float* sm = (float*)&smem[0][0][0][0];  // 128x128 f32 tile (65.5 KB)
#pragma unroll
    for (int m = 0; m < 4; ++m)
#pragma unroll
        for (int n = 0; n < 4; ++n) {
            const int r = moff + m * 16 + fq * 4;
            const int col = noff + n * 16 + frow;
#pragma unroll
            for (int i = 0; i < 4; ++i)
                sm[(size_t)(r + i) * BT + col] = acc[m][n][i];
        }
    __syncthreads();

    const float g = gamma[0];
    // 128 rows x 32 float4-cols = 4096 slots; 16 per thread
#pragma unroll
    for (int j = 0; j < 16; ++j) {
        const int f = tid + 256 * j;
        const int row = f >> 5;         // 0..127 (c-tile row)
        const int c4 = (f & 31) * 4;    // f32 col within tile
        const f32x4 v = *(const f32x4*)&sm[(size_t)row * BT + c4];
        const size_t idx = (size_t)(c0 + row) * N_DIM + n0 + c4;
        const f32x4 xv = *(const f32x4*)&Q[idx];
        f32x4 o;
#pragma unroll
        for (int q = 0; q < 4; ++q) o[q] = g * v[q] + xv[q];
        *(f32x4*)&Ob[idx] = o;
    }
}

// ---------------------------------------------------------------------------
extern "C" void kernel_launch(void* const* d_in, const int* in_sizes, int n_in,
                              void* d_out, int out_size, void* d_ws, size_t ws_size,
                              hipStream_t stream) {
    const float* x = (const float*)d_in[0];
    const float* gamma = (const float*)d_in[1];
    float* out = (float*)d_out;

    // ws layout: [mx 2KB][pmax 64KB][pad to 128KB][partials SK * 16.78MB]
    const size_t HDR = 128 * 1024;
    const size_t PSZ = (size_t)B_DIM * C_DIM * C_DIM * sizeof(float);
    int kshift = 0;
    if (ws_size >= HDR + 8 * PSZ) kshift = 3;
    else if (ws_size >= HDR + 4 * PSZ) kshift = 2;
    else if (ws_size >= HDR + 2 * PSZ) kshift = 1;
    const int SK = 1 << kshift;

    float* mx = (float*)d_ws;
    float* pmax = mx + C_DIM;
    float* part = (float*)((char*)d_ws + HDR);

    dim3 g1(10, 1, B_DIM * SK);
    gram_kernel<<<g1, 256, 0, stream>>>(x, part, kshift);

    colmax1<<<dim3(2, 32), 256, 0, stream>>>(part, pmax, SK);
    colmax2<<<2, 256, 0, stream>>>(pmax, mx);

    softmax_kernel<<<(B_DIM * C_DIM) / 4, 256, 0, stream>>>(part, mx, SK);

    gemm2_kernel<<<2048, 256, 0, stream>>>((const unsigned short*)part, x, gamma, out);
}

// Round 16
// 235.214 us; speedup vs baseline: 1.1829x; 1.1829x over previous
//
#include <hip/hip_runtime.h>
#include <cstdint>

#define B_DIM 16
#define C_DIM 512
#define N_DIM 4096

typedef __bf16 bf16x8 __attribute__((ext_vector_type(8)));
typedef unsigned short u16x8 __attribute__((ext_vector_type(8)));
typedef unsigned short u16x4 __attribute__((ext_vector_type(4)));
typedef unsigned int u32x4 __attribute__((ext_vector_type(4)));
typedef unsigned int u32x2 __attribute__((ext_vector_type(2)));
typedef float f32x4 __attribute__((ext_vector_type(4)));

__device__ __forceinline__ bf16x8 as_bf(u16x8 v) { return __builtin_bit_cast(bf16x8, v); }

// [hi16(ub) : hi16(ua)] in one v_perm_b32 (ua -> low half)
__device__ __forceinline__ unsigned pack_hi(unsigned ua, unsigned ub) {
    return __builtin_amdgcn_perm(ub, ua, 0x07060302u);
}
__device__ __forceinline__ unsigned rne_pack(float a, float b) {
    unsigned ua = __float_as_uint(a);
    ua += 0x7fffu + ((ua >> 16) & 1u);
    unsigned ub = __float_as_uint(b);
    ub += 0x7fffu + ((ub >> 16) & 1u);
    return pack_hi(ua, ub);
}

#define BT 128
#define BK 32
#define BKP 40   // gram LDS row pad (ushorts)
#define GK 64    // gemm2 K-step
#define GKP 72   // gemm2 LDS row pad

// ---------------------------------------------------------------------------
// Kernel 1: partial Gram  E_s[c,d] = sum_{n in slice s} Q[n,c] Q[n,d]
// Split bf16 (truncating): E ~ hi*hi + hi*lo + lo*hi.  Upper-triangle tiles
// only, mirrored on store.  SK=8 when ws allows.  BK=32 / 40KB LDS is the
// measured optimum: GBK=64 (r15) cut co-residency 3->2 blocks/CU and doubled
// prefetch VGPR (92->144) -> 103->145us.  gram's column-strided scalar
// staging needs the cross-block TLP more than fewer barriers.
// NOTE (r11/r12): do NOT pre-materialize a bf16 x copy for gemm2.
// Plain launch_bounds: (256,4) caps VGPR at 64 -> spill catastrophe (r3).
// ---------------------------------------------------------------------------
__global__ __launch_bounds__(256) void gram_kernel(const float* __restrict__ x,
                                                   float* __restrict__ part, int kshift) {
    const int nwg = 10 * gridDim.z;
    const int chunk = nwg >> 3;
    const int flat = blockIdx.x + 10 * blockIdx.z;
    const int swz = (flat & 7) * chunk + (flat >> 3);
    const int tile = swz % 10;
    const int z = swz / 10;
    const int s = z & ((1 << kshift) - 1);
    const int b = z >> kshift;
    static const int TI[10] = {0, 0, 0, 0, 1, 1, 1, 2, 2, 3};
    static const int TJ[10] = {0, 1, 2, 3, 1, 2, 3, 2, 3, 3};
    const int c0 = TI[tile] * BT;
    const int d0 = TJ[tile] * BT;
    const bool diag = (c0 == d0);

    const float* __restrict__ Q = x + (size_t)b * (N_DIM * C_DIM);
    float* __restrict__ E = part + ((size_t)s * B_DIM + b) * (C_DIM * C_DIM);

    __shared__ unsigned short lAh[BT][BKP];
    __shared__ unsigned short lAl[BT][BKP];
    __shared__ unsigned short lBh[BT][BKP];
    __shared__ unsigned short lBl[BT][BKP];

    const int tid = threadIdx.x;
    const int lane = tid & 63;
    const int w = tid >> 6;
    const int moff = (w & 1) * 64;
    const int noff = (w >> 1) * 64;
    const int frow = lane & 15;
    const int fk = (lane >> 4) * 8;

    f32x4 acc[4][4];
#pragma unroll
    for (int m = 0; m < 4; ++m)
#pragma unroll
        for (int n = 0; n < 4; ++n) acc[m][n] = (f32x4){0.f, 0.f, 0.f, 0.f};

    const int cc = tid & 127;
    const int kh = tid >> 7;

    const int klen = N_DIM >> kshift;
    const float* gA = Q + (size_t)(s * klen + kh * 16) * C_DIM + (c0 + cc);
    const float* gB = Q + (size_t)(s * klen + kh * 16) * C_DIM + (d0 + cc);

    const unsigned short(*pBh)[BKP] = diag ? lAh : lBh;
    const unsigned short(*pBl)[BKP] = diag ? lAl : lBl;

    float av[16], bv[16];
#pragma unroll
    for (int i = 0; i < 16; ++i) av[i] = gA[(size_t)i * C_DIM];
    if (!diag) {
#pragma unroll
        for (int i = 0; i < 16; ++i) bv[i] = gB[(size_t)i * C_DIM];
    }
    gA += (size_t)BK * C_DIM;
    gB += (size_t)BK * C_DIM;

    const int T = klen / BK;
    for (int t = 0; t < T; ++t) {
        // convert current prefetched tile (v_perm packing)
        u32x4 ah[2], al[2], bh[2], bl[2];
#pragma unroll
        for (int g = 0; g < 2; ++g)
#pragma unroll
            for (int p = 0; p < 4; ++p) {
                const int j = g * 8 + p * 2;
                unsigned u0 = __float_as_uint(av[j]), u1 = __float_as_uint(av[j + 1]);
                ah[g][p] = pack_hi(u0, u1);
                float r0 = av[j] - __uint_as_float(u0 & 0xffff0000u);
                float r1 = av[j + 1] - __uint_as_float(u1 & 0xffff0000u);
                al[g][p] = pack_hi(__float_as_uint(r0), __float_as_uint(r1));
            }
        if (!diag) {
#pragma unroll
            for (int g = 0; g < 2; ++g)
#pragma unroll
                for (int p = 0; p < 4; ++p) {
                    const int j = g * 8 + p * 2;
                    unsigned u0 = __float_as_uint(bv[j]), u1 = __float_as_uint(bv[j + 1]);
                    bh[g][p] = pack_hi(u0, u1);
                    float r0 = bv[j] - __uint_as_float(u0 & 0xffff0000u);
                    float r1 = bv[j + 1] - __uint_as_float(u1 & 0xffff0000u);
                    bl[g][p] = pack_hi(__float_as_uint(r0), __float_as_uint(r1));
                }
        }

        __syncthreads();  // previous iteration's LDS reads done
        *(u16x8*)&lAh[cc][kh * 16]     = __builtin_bit_cast(u16x8, ah[0]);
        *(u16x8*)&lAh[cc][kh * 16 + 8] = __builtin_bit_cast(u16x8, ah[1]);
        *(u16x8*)&lAl[cc][kh * 16]     = __builtin_bit_cast(u16x8, al[0]);
        *(u16x8*)&lAl[cc][kh * 16 + 8] = __builtin_bit_cast(u16x8, al[1]);
        if (!diag) {
            *(u16x8*)&lBh[cc][kh * 16]     = __builtin_bit_cast(u16x8, bh[0]);
            *(u16x8*)&lBh[cc][kh * 16 + 8] = __builtin_bit_cast(u16x8, bh[1]);
            *(u16x8*)&lBl[cc][kh * 16]     = __builtin_bit_cast(u16x8, bl[0]);
            *(u16x8*)&lBl[cc][kh * 16 + 8] = __builtin_bit_cast(u16x8, bl[1]);
        }
        __syncthreads();

        // issue next tile's loads; latency hides under MFMA below
        if (t + 1 < T) {
#pragma unroll
            for (int i = 0; i < 16; ++i) av[i] = gA[(size_t)i * C_DIM];
            if (!diag) {
#pragma unroll
                for (int i = 0; i < 16; ++i) bv[i] = gB[(size_t)i * C_DIM];
            }
            gA += (size_t)BK * C_DIM;
            gB += (size_t)BK * C_DIM;
        }

        bf16x8 fbh[4], fbl[4];
#pragma unroll
        for (int n = 0; n < 4; ++n) {
            fbh[n] = as_bf(*(const u16x8*)&pBh[noff + n * 16 + frow][fk]);
            fbl[n] = as_bf(*(const u16x8*)&pBl[noff + n * 16 + frow][fk]);
        }
#pragma unroll
        for (int m = 0; m < 4; ++m) {
            bf16x8 fah = as_bf(*(const u16x8*)&lAh[moff + m * 16 + frow][fk]);
            bf16x8 fal = as_bf(*(const u16x8*)&lAl[moff + m * 16 + frow][fk]);
#pragma unroll
            for (int n = 0; n < 4; ++n) {
                acc[m][n] = __builtin_amdgcn_mfma_f32_16x16x32_bf16(fah, fbh[n], acc[m][n], 0, 0, 0);
                acc[m][n] = __builtin_amdgcn_mfma_f32_16x16x32_bf16(fah, fbl[n], acc[m][n], 0, 0, 0);
                acc[m][n] = __builtin_amdgcn_mfma_f32_16x16x32_bf16(fal, fbh[n], acc[m][n], 0, 0, 0);
            }
        }
    }

#pragma unroll
    for (int m = 0; m < 4; ++m)
#pragma unroll
        for (int n = 0; n < 4; ++n) {
            const int r = c0 + moff + m * 16 + (lane >> 4) * 4;
            const int col = d0 + noff + n * 16 + frow;
#pragma unroll
            for (int i = 0; i < 4; ++i)
                E[(size_t)(r + i) * C_DIM + col] = acc[m][n][i];
        }
    if (!diag) {
#pragma unroll
        for (int m = 0; m < 4; ++m)
#pragma unroll
            for (int n = 0; n < 4; ++n) {
                const int r = c0 + moff + m * 16 + (lane >> 4) * 4;
                const int col = d0 + noff + n * 16 + frow;
#pragma unroll
                for (int i = 0; i < 4; ++i)
                    E[(size_t)col * C_DIM + (r + i)] = acc[m][n][i];
            }
    }
}

// ---------------------------------------------------------------------------
// Kernel 2a/2b: column max of batch-0 energy (sum of partials on the fly)
// ---------------------------------------------------------------------------
__global__ __launch_bounds__(256) void colmax1(const float* __restrict__ part,
                                               float* __restrict__ pmax, int sk) {
    const int d = blockIdx.x * 256 + threadIdx.x;
    const int cg = blockIdx.y;
    const size_t PS = (size_t)B_DIM * C_DIM * C_DIM;
    float m = -3.4e38f;
    for (int c = cg * 16; c < cg * 16 + 16; ++c) {
        float e = 0.f;
        for (int s = 0; s < sk; ++s) e += part[(size_t)s * PS + (size_t)c * C_DIM + d];
        m = fmaxf(m, e);
    }
    pmax[cg * C_DIM + d] = m;
}

__global__ __launch_bounds__(256) void colmax2(const float* __restrict__ pmax,
                                               float* __restrict__ mx) {
    const int d = blockIdx.x * 256 + threadIdx.x;
    float m = pmax[d];
#pragma unroll
    for (int g = 1; g < 32; ++g) m = fmaxf(m, pmax[g * C_DIM + d]);
    mx[d] = m;
}

// ---------------------------------------------------------------------------
// Kernel 3: row softmax of (mx[d] - sum_s E_s[b,c,d]).
// Emits bf16 (RNE) att, striped into the BACK HALF of each partial-0 row:
// u16 index wid*1024 + 512 + d.  Race-free: each wave fully reads its row
// before any lane writes it; no other row touches it.
// ---------------------------------------------------------------------------
__global__ __launch_bounds__(256) void softmax_kernel(float* __restrict__ part,
                                                      const float* __restrict__ mx, int sk) {
    const int wid = blockIdx.x * 4 + (threadIdx.x >> 6);  // row index in [0, B*C)
    const int lane = threadIdx.x & 63;
    const size_t PS = (size_t)B_DIM * C_DIM * C_DIM;

    f32x4 ea = (f32x4){0.f, 0.f, 0.f, 0.f}, eb = ea;
    for (int s = 0; s < sk; ++s) {
        const f32x4* row = (const f32x4*)(part + (size_t)s * PS + (size_t)wid * C_DIM + lane * 8);
        ea += row[0];
        eb += row[1];
    }
    f32x4 ma = *(const f32x4*)&mx[lane * 8];
    f32x4 mb = *(const f32x4*)&mx[lane * 8 + 4];

    float v[8];
#pragma unroll
    for (int j = 0; j < 4; ++j) v[j] = ma[j] - ea[j];
#pragma unroll
    for (int j = 0; j < 4; ++j) v[4 + j] = mb[j] - eb[j];

    float rm = v[0];
#pragma unroll
    for (int j = 1; j < 8; ++j) rm = fmaxf(rm, v[j]);
#pragma unroll
    for (int st = 1; st < 64; st <<= 1) rm = fmaxf(rm, __shfl_xor(rm, st));

    float p[8];
    float sum = 0.f;
#pragma unroll
    for (int j = 0; j < 8; ++j) {
        p[j] = expf(v[j] - rm);
        sum += p[j];
    }
#pragma unroll
    for (int st = 1; st < 64; st <<= 1) sum += __shfl_xor(sum, st);

    const float inv = 1.f / sum;
    u32x4 o;
#pragma unroll
    for (int q = 0; q < 4; ++q) o[q] = rne_pack(p[2 * q] * inv, p[2 * q + 1] * inv);
    unsigned short* arow = (unsigned short*)part + (size_t)wid * 1024 + 512;
    *(u16x8*)&arow[lane * 8] = __builtin_bit_cast(u16x8, o);
}

// ---------------------------------------------------------------------------
// Kernel 4: out[b,c,n] = gamma * sum_d att[b,c,d] * Q[n,d] + x[b,c,n]
// r10's measured-best K-loop (128x128, 256 thr, GK=64, dbuf, tracked-reg
// staging, XCD swizzle, plain bounds) + r14's LDS-transposed float4 epilogue.
// ---------------------------------------------------------------------------
__global__ __launch_bounds__(256) void gemm2_kernel(const unsigned short* __restrict__ att16,
                                                    const float* __restrict__ x,
                                                    const float* __restrict__ gamma,
                                                    float* __restrict__ out) {
    const int flat = blockIdx.x;
    const int swz = (flat & 7) * 256 + (flat >> 3);  // 2048 % 8 == 0: bijective
    const int c0 = (swz & 3) * BT;
    const int n0 = ((swz >> 2) & 31) * BT;
    const int b = swz >> 7;

    const float* __restrict__ Q = x + (size_t)b * (N_DIM * C_DIM);
    float* __restrict__ Ob = out + (size_t)b * (C_DIM * N_DIM);
    const unsigned short* __restrict__ Ab = att16 + (size_t)(b * C_DIM + c0) * 1024 + 512;

    // [buf][A=0/B=1][row][col]; also reused as 128x128 f32 tile in epilogue
    __shared__ unsigned short smem[2][2][BT][GKP];  // 73.7 KB

    const int tid = threadIdx.x;
    const int lane = tid & 63;
    const int w = tid >> 6;
    const int moff = (w & 1) * 64;
    const int noff = (w >> 1) * 64;
    const int frow = lane & 15;
    const int fq = lane >> 4;  // 0..3
    const int fk = fq * 8;

    f32x4 acc[4][4];
#pragma unroll
    for (int m = 0; m < 4; ++m)
#pragma unroll
        for (int n = 0; n < 4; ++n) acc[m][n] = (f32x4){0.f, 0.f, 0.f, 0.f};

    // A staging: f = tid + 256*i (i<4): row f>>3 (0..127), u16 chunk (f&7)*8
    const int ar = tid >> 3;          // +32*i
    const int ac = (tid & 7) * 8;     // u16 col
    const int br = ar;
    const int bc = (tid & 7) * 8;     // f32 col

    u16x8 pa[4];
    float4 rb[4][2];
#pragma unroll
    for (int i = 0; i < 4; ++i)
        pa[i] = *(const u16x8*)&Ab[(size_t)(ar + 32 * i) * 1024 + ac];
#pragma unroll
    for (int i = 0; i < 4; ++i) {
        rb[i][0] = *(const float4*)&Q[(size_t)(n0 + br + 32 * i) * C_DIM + bc];
        rb[i][1] = *(const float4*)&Q[(size_t)(n0 + br + 32 * i) * C_DIM + bc + 4];
    }
#pragma unroll
    for (int i = 0; i < 4; ++i)
        *(u16x8*)&smem[0][0][ar + 32 * i][ac] = pa[i];
#pragma unroll
    for (int i = 0; i < 4; ++i) {
        u32x4 pk = {pack_hi(__float_as_uint(rb[i][0].x), __float_as_uint(rb[i][0].y)),
                    pack_hi(__float_as_uint(rb[i][0].z), __float_as_uint(rb[i][0].w)),
                    pack_hi(__float_as_uint(rb[i][1].x), __float_as_uint(rb[i][1].y)),
                    pack_hi(__float_as_uint(rb[i][1].z), __float_as_uint(rb[i][1].w))};
        *(u16x8*)&smem[0][1][br + 32 * i][bc] = __builtin_bit_cast(u16x8, pk);
    }

    int cur = 0;
    for (int t = 0; t < 8; ++t) {
        __syncthreads();  // buf[cur] staged; prev iteration's reads done
        if (t < 7) {
            const int k1 = (t + 1) * GK;
#pragma unroll
            for (int i = 0; i < 4; ++i)
                pa[i] = *(const u16x8*)&Ab[(size_t)(ar + 32 * i) * 1024 + k1 + ac];
#pragma unroll
            for (int i = 0; i < 4; ++i) {
                rb[i][0] = *(const float4*)&Q[(size_t)(n0 + br + 32 * i) * C_DIM + k1 + bc];
                rb[i][1] = *(const float4*)&Q[(size_t)(n0 + br + 32 * i) * C_DIM + k1 + bc + 4];
            }
        }

#pragma unroll
        for (int sub = 0; sub < 2; ++sub) {
            const int sk = sub * 32 + fk;
            bf16x8 fb[4];
#pragma unroll
            for (int n = 0; n < 4; ++n)
                fb[n] = as_bf(*(const u16x8*)&smem[cur][1][noff + n * 16 + frow][sk]);
#pragma unroll
            for (int m = 0; m < 4; ++m) {
                const bf16x8 fa = as_bf(*(const u16x8*)&smem[cur][0][moff + m * 16 + frow][sk]);
#pragma unroll
                for (int n = 0; n < 4; ++n)
                    acc[m][n] = __builtin_amdgcn_mfma_f32_16x16x32_bf16(fa, fb[n], acc[m][n], 0, 0, 0);
            }
        }

        if (t < 7) {
            const int nb = cur ^ 1;
#pragma unroll
            for (int i = 0; i < 4; ++i)
                *(u16x8*)&smem[nb][0][ar + 32 * i][ac] = pa[i];
#pragma unroll
            for (int i = 0; i < 4; ++i) {
                u32x4 pk = {pack_hi(__float_as_uint(rb[i][0].x), __float_as_uint(rb[i][0].y)),
                            pack_hi(__float_as_uint(rb[i][0].z), __float_as_uint(rb[i][0].w)),
                            pack_hi(__float_as_uint(rb[i][1].x), __float_as_uint(rb[i][1].y)),
                            pack_hi(__float_as_uint(rb[i][1].z), __float_as_uint(rb[i][1].w))};
                *(u16x8*)&smem[nb][1][br + 32 * i][bc] = __builtin_bit_cast(u16x8, pk);
            }
        }
        cur ^= 1;
    }

    // -------- epilogue: transpose acc through LDS, then float4 x/out --------
    __syncthreads();  // all K-loop LDS reads complete; LDS is free
    float* sm = (float*)&smem[0][0][0][0];  // 128x128 f32 tile (65.5 KB)
#pragma unroll
    for (int m = 0; m < 4; ++m)
#pragma unroll
        for (int n = 0; n < 4; ++n) {
            const int r = moff + m * 16 + fq * 4;
            const int col = noff + n * 16 + frow;
#pragma unroll
            for (int i = 0; i < 4; ++i)
                sm[(size_t)(r + i) * BT + col] = acc[m][n][i];
        }
    __syncthreads();

    const float g = gamma[0];
    // 128 rows x 32 float4-cols = 4096 slots; 16 per thread
#pragma unroll
    for (int j = 0; j < 16; ++j) {
        const int f = tid + 256 * j;
        const int row = f >> 5;         // 0..127 (c-tile row)
        const int c4 = (f & 31) * 4;    // f32 col within tile
        const f32x4 v = *(const f32x4*)&sm[(size_t)row * BT + c4];
        const size_t idx = (size_t)(c0 + row) * N_DIM + n0 + c4;
        const f32x4 xv = *(const f32x4*)&Q[idx];
        f32x4 o;
#pragma unroll
        for (int q = 0; q < 4; ++q) o[q] = g * v[q] + xv[q];
        *(f32x4*)&Ob[idx] = o;
    }
}

// ---------------------------------------------------------------------------
extern "C" void kernel_launch(void* const* d_in, const int* in_sizes, int n_in,
                              void* d_out, int out_size, void* d_ws, size_t ws_size,
                              hipStream_t stream) {
    const float* x = (const float*)d_in[0];
    const float* gamma = (const float*)d_in[1];
    float* out = (float*)d_out;

    // ws layout: [mx 2KB][pmax 64KB][pad to 128KB][partials SK * 16.78MB]
    const size_t HDR = 128 * 1024;
    const size_t PSZ = (size_t)B_DIM * C_DIM * C_DIM * sizeof(float);
    int kshift = 0;
    if (ws_size >= HDR + 8 * PSZ) kshift = 3;
    else if (ws_size >= HDR + 4 * PSZ) kshift = 2;
    else if (ws_size >= HDR + 2 * PSZ) kshift = 1;
    const int SK = 1 << kshift;

    float* mx = (float*)d_ws;
    float* pmax = mx + C_DIM;
    float* part = (float*)((char*)d_ws + HDR);

    dim3 g1(10, 1, B_DIM * SK);
    gram_kernel<<<g1, 256, 0, stream>>>(x, part, kshift);

    colmax1<<<dim3(2, 32), 256, 0, stream>>>(part, pmax, SK);
    colmax2<<<2, 256, 0, stream>>>(pmax, mx);

    softmax_kernel<<<(B_DIM * C_DIM) / 4, 256, 0, stream>>>(part, mx, SK);

    gemm2_kernel<<<2048, 256, 0, stream>>>((const unsigned short*)part, x, gamma, out);
}